// Round 4
// baseline (148.205 us; speedup 1.0000x reference)
//
#include <hip/hip_runtime.h>
#include <math.h>

#define NN 147456   // 384*384
#define Nn 384
#define Dd 256
#define Cc 12

// stats layout offsets (floats), base = ws + 3*NN
#define SST_S   0     // 144  : sum E_ss over (i in s, j in t)
#define STT     144   // 12   : sum pt_i E_tt pt_j
#define SSTD    156   // 12   : diag of ps^T E_st pt
#define CS      168   // 12
#define CT      180   // 12
#define G_IN    192   // 12
#define G2      204   // 144
#define IBW_IN  348   // 60   : 1/bw for g_in, 5 per class
#define IBW2    408   // 720  : 1/bw for g2, 5 per (s,t)
#define INV_PSS 1128  // 12
#define INV_PTT 1140  // 12
#define INV_CST 1152  // 12
#define INV_CC  1164  // 144
#define ZERO_COUNT 168  // sst_s + stt + sstd must be zeroed (atomic targets)

__device__ __forceinline__ float kern5(float d, const float* __restrict__ ibw) {
    float acc = 0.f;
#pragma unroll
    for (int k = 0; k < 5; k++) {
        float r = fminf(fmaxf(d * ibw[k], 1e-5f), 1e5f);
        acc += __expf(-r);
    }
    return acc;
}

__device__ __forceinline__ float blockReduceSum(float v, float* sh) {
#pragma unroll
    for (int o = 32; o; o >>= 1) v += __shfl_xor(v, o, 64);
    __syncthreads();                       // protect sh reuse across calls
    if ((threadIdx.x & 63) == 0) sh[threadIdx.x >> 6] = v;
    __syncthreads();
    float r = 0.f;
    if (threadIdx.x == 0) {
        int nw = (int)(blockDim.x >> 6);
        for (int w = 0; w < nw; w++) r += sh[w];
    }
    return r;
}

// ---------- kernel 1: three pairwise-distance matrices ----------
// z=0: E_ss = dist(src,src); z=1: E_tt = dist(tgt,tgt); z=2: E_st = dist(src,tgt)
__global__ __launch_bounds__(256) void cdist_kernel(
        const float* __restrict__ sx, const float* __restrict__ tx,
        float* __restrict__ Ebase) {
    int z = blockIdx.z;
    const float* X = (z == 1) ? tx : sx;
    const float* Y = (z == 0) ? sx : tx;
    float* Eo = Ebase + z * NN;
    __shared__ float As[32][33];
    __shared__ float Bs[32][33];
    int i0 = blockIdx.y * 32, j0 = blockIdx.x * 32;
    int tid = threadIdx.x;
    int tj = tid & 31, ti = tid >> 5;  // 32 cols x 8 rows
    float acc[4] = {0.f, 0.f, 0.f, 0.f};
    for (int kk = 0; kk < Dd; kk += 32) {
#pragma unroll
        for (int p = 0; p < 4; p++) {
            int idx = tid + p * 256;
            int r = idx >> 5, k = idx & 31;
            As[r][k] = X[(i0 + r) * Dd + kk + k];
            Bs[r][k] = Y[(j0 + r) * Dd + kk + k];
        }
        __syncthreads();
#pragma unroll
        for (int m = 0; m < 4; m++) {
            int r = ti + m * 8;
            float a = 0.f;
#pragma unroll
            for (int k = 0; k < 32; k++) {
                float d = As[r][k] - Bs[tj][k];
                a = fmaf(d, d, a);
            }
            acc[m] += a;
        }
        __syncthreads();
    }
#pragma unroll
    for (int m = 0; m < 4; m++)
        Eo[(i0 + ti + m * 8) * Nn + j0 + tj] = sqrtf(acc[m]);
}

// ---------- kernel 2: class-weighted distance sums ----------
// grid (12 row-chunks, 3 matrices), block 384 (thread = column j)
__global__ __launch_bounds__(384) void stats_kernel(
        const float* __restrict__ Ebase, const int* __restrict__ ys,
        const float* __restrict__ pt, float* __restrict__ st) {
    int z = blockIdx.y;
    int i0 = blockIdx.x * 32;
    int j = threadIdx.x;
    const float* E = Ebase + z * NN;
    __shared__ int ysh[32];
    __shared__ float ptish[32 * 12];
    __shared__ float red[144];
    if (j < 32) ysh[j] = ys[i0 + j];
    if (j < 144) red[j] = 0.f;
    ptish[j] = pt[i0 * 12 + j];  // rows i0..i0+31 of pt, contiguous 384 floats
    __syncthreads();

    float acc[12];
#pragma unroll
    for (int c = 0; c < 12; c++) acc[c] = 0.f;

    if (z == 0) {
        // sst_s[s][t] = sum_{i in s, j in t} E_ss[i,j]
        for (int r = 0; r < 32; r++) {
            int s = ysh[r];
            float e = E[(i0 + r) * Nn + j];
#pragma unroll
            for (int c = 0; c < 12; c++) acc[c] += (s == c) ? e : 0.f;
        }
        int t = ys[j];
#pragma unroll
        for (int c = 0; c < 12; c++) atomicAdd(&red[c * 12 + t], acc[c]);
        __syncthreads();
        if (j < 144) atomicAdd(&st[SST_S + j], red[j]);
    } else if (z == 1) {
        // stt[c] = sum_ij pt[i,c] E_tt[i,j] pt[j,c]
        for (int r = 0; r < 32; r++) {
            float e = E[(i0 + r) * Nn + j];
#pragma unroll
            for (int c = 0; c < 12; c++) acc[c] = fmaf(e, ptish[r * 12 + c], acc[c]);
        }
#pragma unroll
        for (int c = 0; c < 12; c++) {
            float v = acc[c] * pt[j * 12 + c];
#pragma unroll
            for (int o = 32; o; o >>= 1) v += __shfl_xor(v, o, 64);
            if ((j & 63) == 0) atomicAdd(&red[c], v);
        }
        __syncthreads();
        if (j < 12) atomicAdd(&st[STT + j], red[j]);
    } else {
        // sstd[c] = sum_{i in c, j} E_st[i,j] pt[j,c]
        for (int r = 0; r < 32; r++) {
            int s = ysh[r];
            float e = E[(i0 + r) * Nn + j];
#pragma unroll
            for (int c = 0; c < 12; c++) acc[c] += (s == c) ? e : 0.f;
        }
#pragma unroll
        for (int c = 0; c < 12; c++) {
            float v = acc[c] * pt[j * 12 + c];
#pragma unroll
            for (int o = 32; o; o >>= 1) v += __shfl_xor(v, o, 64);
            if ((j & 63) == 0) atomicAdd(&red[c], v);
        }
        __syncthreads();
        if (j < 12) atomicAdd(&st[SSTD + j], red[j]);
    }
}

// ---------- kernel 3: counts, gammas, inverse-bandwidth tables ----------
__global__ __launch_bounds__(256) void prep_kernel(
        const int* __restrict__ ys, const float* __restrict__ pt,
        float* __restrict__ st) {
    const float MUP[5] = {0.25f, 0.5f, 1.f, 2.f, 4.f};
    __shared__ float csh[12], cth[12];
    int tid = threadIdx.x;
    if (tid < 12) { csh[tid] = 0.f; cth[tid] = 0.f; }
    __syncthreads();
    float myc[12], myt[12];
#pragma unroll
    for (int c = 0; c < 12; c++) { myc[c] = 0.f; myt[c] = 0.f; }
    for (int i = tid; i < Nn; i += 256) {
        int y = ys[i];
#pragma unroll
        for (int c = 0; c < 12; c++) {
            myc[c] += (y == c) ? 1.f : 0.f;
            myt[c] += pt[i * 12 + c];
        }
    }
#pragma unroll
    for (int c = 0; c < 12; c++) {
        float a = myc[c], b = myt[c];
#pragma unroll
        for (int o = 32; o; o >>= 1) { a += __shfl_xor(a, o, 64); b += __shfl_xor(b, o, 64); }
        if ((tid & 63) == 0) { atomicAdd(&csh[c], a); atomicAdd(&cth[c], b); }
    }
    __syncthreads();

    if (tid < 12) {
        float cs = csh[tid], ct = cth[tid];
        st[CS + tid] = cs;
        st[CT + tid] = ct;
        float sss = st[SST_S + tid * 13];
        float den = (cs + ct) * (cs + ct);
        float g = (sss + st[STT + tid] + 2.f * st[SSTD + tid]) / den;
        st[G_IN + tid] = g;
#pragma unroll
        for (int k = 0; k < 5; k++)
            st[IBW_IN + tid * 5 + k] = 1.f / fmaxf(g * MUP[k], 1e-5f);
        st[INV_PSS + tid] = 1.f / (cs * cs);
        st[INV_PTT + tid] = 1.f / (ct * ct);
        st[INV_CST + tid] = 1.f / (cs * ct);
    }
    if (tid < 144) {
        int s = tid / 12, t = tid % 12;
        float cs = csh[s], ctc = csh[t];
        float sums = st[SST_S + s * 13], sumt = st[SST_S + t * 13];
        float den = (cs + ctc) * (cs + ctc);
        float g2 = (sums + sumt + 2.f * st[SST_S + tid]) / den;
        st[G2 + tid] = g2;
#pragma unroll
        for (int k = 0; k < 5; k++)
            st[IBW2 + tid * 5 + k] = 1.f / fmaxf(g2 * MUP[k], 1e-5f);
        st[INV_CC + tid] = 1.f / (cs * ctc);
    }
}

// ---------- kernel 4: k2 (target-target, soft probs, all classes) ----------
// grid (12 row-chunks, 12 classes), block 384
__global__ __launch_bounds__(384) void k2_kernel(
        const float* __restrict__ Ett, const float* __restrict__ pt,
        const float* __restrict__ st, float* __restrict__ out) {
    int c = blockIdx.y;
    int i0 = blockIdx.x * 32;
    int j = threadIdx.x;
    __shared__ float ptish[32];
    __shared__ float ibwsh[5];
    __shared__ float red[8];
    if (j < 32) ptish[j] = pt[(i0 + j) * 12 + c];
    if (j < 5) ibwsh[j] = st[IBW_IN + c * 5 + j];
    float ptj = pt[j * 12 + c];
    __syncthreads();
    float sum = 0.f;
    for (int r = 0; r < 32; r++) {
        float e = Ett[(i0 + r) * Nn + j];
        float w = ptish[r] * ptj;
        float d = e * w;
        sum = fmaf(kern5(d, ibwsh), w, sum);
    }
    sum = blockReduceSum(sum, red);
    if (j == 0) atomicAdd(&out[0], sum * st[INV_PTT + c] * (1.f / 12.f));
}

// ---------- kernel 5: k3 (source-target, diagonal class pairs) ----------
__global__ __launch_bounds__(384) void k3_kernel(
        const float* __restrict__ Est, const int* __restrict__ ys,
        const float* __restrict__ pt, const float* __restrict__ st,
        float* __restrict__ out) {
    int i0 = blockIdx.x * 32;
    int j = threadIdx.x;
    __shared__ int ysh[32];
    __shared__ float ibwsh[60];
    __shared__ float invsh[12];
    __shared__ float red[8];
    if (j < 32) ysh[j] = ys[i0 + j];
    if (j < 60) ibwsh[j] = st[IBW_IN + j];
    if (j < 12) invsh[j] = st[INV_CST + j];
    __syncthreads();
    float sum = 0.f;
    for (int r = 0; r < 32; r++) {
        int s = ysh[r];                    // wave-uniform per iteration
        float e = Est[(i0 + r) * Nn + j];
        float w = pt[j * 12 + s];
        float d = e * w;
        sum += kern5(d, &ibwsh[s * 5]) * w * invsh[s];
    }
    sum = blockReduceSum(sum, red);
    if (j == 0) atomicAdd(&out[0], sum * (-2.f / 12.f));
}

// ---------- kernel 6: k1 + inter (T1/T2/T3) on E_ss, one-hot masked ----------
__global__ __launch_bounds__(384) void k1t_kernel(
        const float* __restrict__ Ess, const int* __restrict__ ys,
        const float* __restrict__ st, float* __restrict__ out) {
    int i0 = blockIdx.x * 32;
    int j = threadIdx.x;
    __shared__ int ysh[32];
    __shared__ float ibw2sh[720];
    __shared__ float ibwinsh[60];
    __shared__ float invpss[12];
    __shared__ float invcc[144];
    __shared__ float red[8];
    if (j < 32) ysh[j] = ys[i0 + j];
    for (int q = j; q < 720; q += 384) ibw2sh[q] = st[IBW2 + q];
    if (j < 60) ibwinsh[j] = st[IBW_IN + j];
    if (j < 12) invpss[j] = st[INV_PSS + j];
    if (j < 144) invcc[j] = st[INV_CC + j];
    int t = ys[j];
    __syncthreads();
    float si = 0.f, se = 0.f;
    for (int r = 0; r < 32; r++) {
        int s = ysh[r];
        float e = Ess[(i0 + r) * Nn + j];
        if (t == s) {
            // k1 (intra): kern at g_in[s], weight 1/cs^2
            si += kern5(e, &ibwinsh[s * 5]) * invpss[s];
            // T1+T2 (inter): sum over t' != s of kern at g2[s,t']
            float ts = 0.f;
#pragma unroll
            for (int tp = 0; tp < 12; tp++) {
                if (tp == s) continue;
                ts += kern5(e, &ibw2sh[(s * 12 + tp) * 5]);
            }
            se += 2.f * ts * invpss[s];
        } else {
            // T3 (inter): cross-class pair
            se -= 2.f * kern5(e, &ibw2sh[(s * 12 + t) * 5]) * invcc[s * 12 + t];
        }
    }
    si = blockReduceSum(si, red);
    se = blockReduceSum(se, red);
    if (j == 0) {
        atomicAdd(&out[0], si * (1.f / 12.f));
        atomicAdd(&out[1], se * (1.f / 132.f));   // C*C - C = 132
    }
}

extern "C" void kernel_launch(void* const* d_in, const int* in_sizes, int n_in,
                              void* d_out, int out_size, void* d_ws, size_t ws_size,
                              hipStream_t stream) {
    (void)in_sizes; (void)n_in; (void)out_size; (void)ws_size;
    const float* sx = (const float*)d_in[0];   // src_x (384,256) f32
    const float* tx = (const float*)d_in[1];   // tgt_x (384,256) f32
    const int*   ys = (const int*)d_in[2];     // src_y (384,) i32
    const float* pt = (const float*)d_in[3];   // tgt_y (384,12) f32
    float* out = (float*)d_out;                // [intra, inter] f32
    float* ws  = (float*)d_ws;
    float* E   = ws;                           // 3 * NN floats
    float* st  = ws + 3 * NN;                  // stats block

    hipMemsetAsync(st, 0, ZERO_COUNT * sizeof(float), stream);
    hipMemsetAsync(out, 0, 2 * sizeof(float), stream);

    cdist_kernel<<<dim3(12, 12, 3), 256, 0, stream>>>(sx, tx, E);
    stats_kernel<<<dim3(12, 3), 384, 0, stream>>>(E, ys, pt, st);
    prep_kernel<<<1, 256, 0, stream>>>(ys, pt, st);
    k2_kernel<<<dim3(12, 12), 384, 0, stream>>>(E + NN, pt, st, out);
    k3_kernel<<<12, 384, 0, stream>>>(E + 2 * NN, ys, pt, st, out);
    k1t_kernel<<<12, 384, 0, stream>>>(E, ys, st, out);
}

// Round 5
// 146.077 us; speedup vs baseline: 1.0146x; 1.0146x over previous
//
#include <hip/hip_runtime.h>
#include <math.h>

#define NN 147456   // 384*384
#define Nn 384
#define Dd 256
#define Cc 12

// stats layout offsets (floats), base = ws + 3*NN
#define SST_S   0     // 144  : sum E_ss over (i in s, j in t)
#define STT     144   // 12   : sum pt_i E_tt pt_j
#define SSTD    156   // 12   : diag of ps^T E_st pt
#define CS      168   // 12
#define CT      180   // 12
#define G_IN    192   // 12
#define G2      204   // 144
#define IBW_IN  348   // 60   : 1/bw for g_in, 5 per class
#define IBW2    408   // 720  : 1/bw for g2, 5 per (s,t)
#define INV_PSS 1128  // 12
#define INV_PTT 1140  // 12
#define INV_CST 1152  // 12
#define INV_CC  1164  // 144
#define ZERO_COUNT 168  // sst_s + stt + sstd must be zeroed (atomic targets)

__device__ __forceinline__ float kern5(float d, const float* __restrict__ ibw) {
    float acc = 0.f;
#pragma unroll
    for (int k = 0; k < 5; k++) {
        float r = fminf(fmaxf(d * ibw[k], 1e-5f), 1e5f);
        acc += __expf(-r);
    }
    return acc;
}

__device__ __forceinline__ float blockReduceSum(float v, float* sh) {
#pragma unroll
    for (int o = 32; o; o >>= 1) v += __shfl_xor(v, o, 64);
    __syncthreads();                       // protect sh reuse across calls
    if ((threadIdx.x & 63) == 0) sh[threadIdx.x >> 6] = v;
    __syncthreads();
    float r = 0.f;
    if (threadIdx.x == 0) {
        int nw = (int)(blockDim.x >> 6);
        for (int w = 0; w < nw; w++) r += sh[w];
    }
    return r;
}

// ---------- kernel 1: three pairwise-distance matrices ----------
// z=0: E_ss = dist(src,src); z=1: E_tt = dist(tgt,tgt); z=2: E_st = dist(src,tgt)
__global__ __launch_bounds__(256) void cdist_kernel(
        const float* __restrict__ sx, const float* __restrict__ tx,
        float* __restrict__ Ebase) {
    int z = blockIdx.z;
    const float* X = (z == 1) ? tx : sx;
    const float* Y = (z == 0) ? sx : tx;
    float* Eo = Ebase + z * NN;
    __shared__ float As[32][33];
    __shared__ float Bs[32][33];
    int i0 = blockIdx.y * 32, j0 = blockIdx.x * 32;
    int tid = threadIdx.x;
    int tj = tid & 31, ti = tid >> 5;  // 32 cols x 8 rows
    float acc[4] = {0.f, 0.f, 0.f, 0.f};
    for (int kk = 0; kk < Dd; kk += 32) {
#pragma unroll
        for (int p = 0; p < 4; p++) {
            int idx = tid + p * 256;
            int r = idx >> 5, k = idx & 31;
            As[r][k] = X[(i0 + r) * Dd + kk + k];
            Bs[r][k] = Y[(j0 + r) * Dd + kk + k];
        }
        __syncthreads();
#pragma unroll
        for (int m = 0; m < 4; m++) {
            int r = ti + m * 8;
            float a = 0.f;
#pragma unroll
            for (int k = 0; k < 32; k++) {
                float d = As[r][k] - Bs[tj][k];
                a = fmaf(d, d, a);
            }
            acc[m] += a;
        }
        __syncthreads();
    }
#pragma unroll
    for (int m = 0; m < 4; m++)
        Eo[(i0 + ti + m * 8) * Nn + j0 + tj] = sqrtf(acc[m]);
}

// ---------- kernel 2: class-weighted distance sums ----------
// grid (12 row-chunks, 3 matrices), block 384 (thread = column j)
__global__ __launch_bounds__(384) void stats_kernel(
        const float* __restrict__ Ebase, const int* __restrict__ ys,
        const float* __restrict__ pt, float* __restrict__ st) {
    int z = blockIdx.y;
    int i0 = blockIdx.x * 32;
    int j = threadIdx.x;
    const float* E = Ebase + z * NN;
    __shared__ int ysh[32];
    __shared__ float ptish[32 * 12];
    __shared__ float red[144];
    if (j < 32) ysh[j] = ys[i0 + j];
    if (j < 144) red[j] = 0.f;
    ptish[j] = pt[i0 * 12 + j];  // rows i0..i0+31 of pt, contiguous 384 floats
    __syncthreads();

    float acc[12];
#pragma unroll
    for (int c = 0; c < 12; c++) acc[c] = 0.f;

    if (z == 0) {
        // sst_s[s][t] = sum_{i in s, j in t} E_ss[i,j]
        for (int r = 0; r < 32; r++) {
            int s = ysh[r];
            float e = E[(i0 + r) * Nn + j];
#pragma unroll
            for (int c = 0; c < 12; c++) acc[c] += (s == c) ? e : 0.f;
        }
        int t = ys[j];
#pragma unroll
        for (int c = 0; c < 12; c++) atomicAdd(&red[c * 12 + t], acc[c]);
        __syncthreads();
        if (j < 144) atomicAdd(&st[SST_S + j], red[j]);
    } else if (z == 1) {
        // stt[c] = sum_ij pt[i,c] E_tt[i,j] pt[j,c]
        for (int r = 0; r < 32; r++) {
            float e = E[(i0 + r) * Nn + j];
#pragma unroll
            for (int c = 0; c < 12; c++) acc[c] = fmaf(e, ptish[r * 12 + c], acc[c]);
        }
#pragma unroll
        for (int c = 0; c < 12; c++) {
            float v = acc[c] * pt[j * 12 + c];
#pragma unroll
            for (int o = 32; o; o >>= 1) v += __shfl_xor(v, o, 64);
            if ((j & 63) == 0) atomicAdd(&red[c], v);
        }
        __syncthreads();
        if (j < 12) atomicAdd(&st[STT + j], red[j]);
    } else {
        // sstd[c] = sum_{i in c, j} E_st[i,j] pt[j,c]
        for (int r = 0; r < 32; r++) {
            int s = ysh[r];
            float e = E[(i0 + r) * Nn + j];
#pragma unroll
            for (int c = 0; c < 12; c++) acc[c] += (s == c) ? e : 0.f;
        }
#pragma unroll
        for (int c = 0; c < 12; c++) {
            float v = acc[c] * pt[j * 12 + c];
#pragma unroll
            for (int o = 32; o; o >>= 1) v += __shfl_xor(v, o, 64);
            if ((j & 63) == 0) atomicAdd(&red[c], v);
        }
        __syncthreads();
        if (j < 12) atomicAdd(&st[SSTD + j], red[j]);
    }
}

// ---------- kernel 3: counts, gammas, inverse-bandwidth tables ----------
__global__ __launch_bounds__(256) void prep_kernel(
        const int* __restrict__ ys, const float* __restrict__ pt,
        float* __restrict__ st) {
    const float MUP[5] = {0.25f, 0.5f, 1.f, 2.f, 4.f};
    __shared__ float csh[12], cth[12];
    int tid = threadIdx.x;
    if (tid < 12) { csh[tid] = 0.f; cth[tid] = 0.f; }
    __syncthreads();
    float myc[12], myt[12];
#pragma unroll
    for (int c = 0; c < 12; c++) { myc[c] = 0.f; myt[c] = 0.f; }
    for (int i = tid; i < Nn; i += 256) {
        int y = ys[i];
#pragma unroll
        for (int c = 0; c < 12; c++) {
            myc[c] += (y == c) ? 1.f : 0.f;
            myt[c] += pt[i * 12 + c];
        }
    }
#pragma unroll
    for (int c = 0; c < 12; c++) {
        float a = myc[c], b = myt[c];
#pragma unroll
        for (int o = 32; o; o >>= 1) { a += __shfl_xor(a, o, 64); b += __shfl_xor(b, o, 64); }
        if ((tid & 63) == 0) { atomicAdd(&csh[c], a); atomicAdd(&cth[c], b); }
    }
    __syncthreads();

    if (tid < 12) {
        float cs = csh[tid], ct = cth[tid];
        st[CS + tid] = cs;
        st[CT + tid] = ct;
        float sss = st[SST_S + tid * 13];
        float den = (cs + ct) * (cs + ct);
        float g = (sss + st[STT + tid] + 2.f * st[SSTD + tid]) / den;
        st[G_IN + tid] = g;
#pragma unroll
        for (int k = 0; k < 5; k++)
            st[IBW_IN + tid * 5 + k] = 1.f / fmaxf(g * MUP[k], 1e-5f);
        st[INV_PSS + tid] = 1.f / (cs * cs);
        st[INV_PTT + tid] = 1.f / (ct * ct);
        st[INV_CST + tid] = 1.f / (cs * ct);
    }
    if (tid < 144) {
        int s = tid / 12, t = tid % 12;
        float cs = csh[s], ctc = csh[t];
        float sums = st[SST_S + s * 13], sumt = st[SST_S + t * 13];
        float den = (cs + ctc) * (cs + ctc);
        float g2 = (sums + sumt + 2.f * st[SST_S + tid]) / den;
        st[G2 + tid] = g2;
#pragma unroll
        for (int k = 0; k < 5; k++)
            st[IBW2 + tid * 5 + k] = 1.f / fmaxf(g2 * MUP[k], 1e-5f);
        st[INV_CC + tid] = 1.f / (cs * ctc);
    }
}

// ---------- kernel 4: k2 (target-target, soft probs, all classes) ----------
// grid (12 row-chunks, 12 classes), block 384
__global__ __launch_bounds__(384) void k2_kernel(
        const float* __restrict__ Ett, const float* __restrict__ pt,
        const float* __restrict__ st, float* __restrict__ out) {
    int c = blockIdx.y;
    int i0 = blockIdx.x * 32;
    int j = threadIdx.x;
    __shared__ float ptish[32];
    __shared__ float ibwsh[5];
    __shared__ float red[8];
    if (j < 32) ptish[j] = pt[(i0 + j) * 12 + c];
    if (j < 5) ibwsh[j] = st[IBW_IN + c * 5 + j];
    float ptj = pt[j * 12 + c];
    __syncthreads();
    float sum = 0.f;
    for (int r = 0; r < 32; r++) {
        float e = Ett[(i0 + r) * Nn + j];
        float w = ptish[r] * ptj;
        float d = e * w;
        sum = fmaf(kern5(d, ibwsh), w, sum);
    }
    sum = blockReduceSum(sum, red);
    if (j == 0) atomicAdd(&out[0], sum * st[INV_PTT + c] * (1.f / 12.f));
}

// ---------- kernel 5: k3 (source-target, diagonal class pairs) ----------
__global__ __launch_bounds__(384) void k3_kernel(
        const float* __restrict__ Est, const int* __restrict__ ys,
        const float* __restrict__ pt, const float* __restrict__ st,
        float* __restrict__ out) {
    int i0 = blockIdx.x * 32;
    int j = threadIdx.x;
    __shared__ int ysh[32];
    __shared__ float ibwsh[60];
    __shared__ float invsh[12];
    __shared__ float red[8];
    if (j < 32) ysh[j] = ys[i0 + j];
    if (j < 60) ibwsh[j] = st[IBW_IN + j];
    if (j < 12) invsh[j] = st[INV_CST + j];
    __syncthreads();
    float sum = 0.f;
    for (int r = 0; r < 32; r++) {
        int s = ysh[r];                    // wave-uniform per iteration
        float e = Est[(i0 + r) * Nn + j];
        float w = pt[j * 12 + s];
        float d = e * w;
        sum += kern5(d, &ibwsh[s * 5]) * w * invsh[s];
    }
    sum = blockReduceSum(sum, red);
    if (j == 0) atomicAdd(&out[0], sum * (-2.f / 12.f));
}

// ---------- kernel 6: k1 + inter (T1/T2/T3) on E_ss, one-hot masked ----------
__global__ __launch_bounds__(384) void k1t_kernel(
        const float* __restrict__ Ess, const int* __restrict__ ys,
        const float* __restrict__ st, float* __restrict__ out) {
    int i0 = blockIdx.x * 32;
    int j = threadIdx.x;
    __shared__ int ysh[32];
    __shared__ float ibw2sh[720];
    __shared__ float ibwinsh[60];
    __shared__ float invpss[12];
    __shared__ float invcc[144];
    __shared__ float red[8];
    if (j < 32) ysh[j] = ys[i0 + j];
    for (int q = j; q < 720; q += 384) ibw2sh[q] = st[IBW2 + q];
    if (j < 60) ibwinsh[j] = st[IBW_IN + j];
    if (j < 12) invpss[j] = st[INV_PSS + j];
    if (j < 144) invcc[j] = st[INV_CC + j];
    int t = ys[j];
    __syncthreads();
    float si = 0.f, se = 0.f;
    for (int r = 0; r < 32; r++) {
        int s = ysh[r];
        float e = Ess[(i0 + r) * Nn + j];
        if (t == s) {
            // k1 (intra): kern at g_in[s], weight 1/cs^2
            si += kern5(e, &ibwinsh[s * 5]) * invpss[s];
            // T1+T2 (inter): sum over t' != s of kern at g2[s,t']
            float ts = 0.f;
#pragma unroll
            for (int tp = 0; tp < 12; tp++) {
                if (tp == s) continue;
                ts += kern5(e, &ibw2sh[(s * 12 + tp) * 5]);
            }
            se += 2.f * ts * invpss[s];
        } else {
            // T3 (inter): cross-class pair
            se -= 2.f * kern5(e, &ibw2sh[(s * 12 + t) * 5]) * invcc[s * 12 + t];
        }
    }
    si = blockReduceSum(si, red);
    se = blockReduceSum(se, red);
    if (j == 0) {
        atomicAdd(&out[0], si * (1.f / 12.f));
        atomicAdd(&out[1], se * (1.f / 132.f));   // C*C - C = 132
    }
}

extern "C" void kernel_launch(void* const* d_in, const int* in_sizes, int n_in,
                              void* d_out, int out_size, void* d_ws, size_t ws_size,
                              hipStream_t stream) {
    (void)in_sizes; (void)n_in; (void)out_size; (void)ws_size;
    const float* sx = (const float*)d_in[0];   // src_x (384,256) f32
    const float* tx = (const float*)d_in[1];   // tgt_x (384,256) f32
    const int*   ys = (const int*)d_in[2];     // src_y (384,) i32
    const float* pt = (const float*)d_in[3];   // tgt_y (384,12) f32
    float* out = (float*)d_out;                // [intra, inter] f32
    float* ws  = (float*)d_ws;
    float* E   = ws;                           // 3 * NN floats
    float* st  = ws + 3 * NN;                  // stats block

    hipMemsetAsync(st, 0, ZERO_COUNT * sizeof(float), stream);
    hipMemsetAsync(out, 0, 2 * sizeof(float), stream);

    cdist_kernel<<<dim3(12, 12, 3), 256, 0, stream>>>(sx, tx, E);
    stats_kernel<<<dim3(12, 3), 384, 0, stream>>>(E, ys, pt, st);
    prep_kernel<<<1, 256, 0, stream>>>(ys, pt, st);
    k2_kernel<<<dim3(12, 12), 384, 0, stream>>>(E + NN, pt, st, out);
    k3_kernel<<<12, 384, 0, stream>>>(E + 2 * NN, ys, pt, st, out);
    k1t_kernel<<<12, 384, 0, stream>>>(E, ys, st, out);
}

// Round 6
// 52.356 us; speedup vs baseline: 2.8307x; 2.7901x over previous
//
#include <hip/hip_runtime.h>
#include <math.h>

#define NN 147456   // 384*384
#define Nn 384
#define Dd 256
#define Cc 12

// stats layout offsets (floats), base = ws + 3*NN
#define SST_S   0     // 144  : sum E_ss over (i in s, j in t)
#define STT     144   // 12   : sum pt_i E_tt pt_j
#define SSTD    156   // 12   : diag of ps^T E_st pt
#define CS      168   // 12
#define CT      180   // 12
#define G_IN    192   // 12
#define G2      204   // 144
#define IBW_IN  348   // 60   : 1/bw for g_in, 5 per class
#define IBW2    408   // 720  : 1/bw for g2, 5 per (s,t)
#define INV_PSS 1128  // 12
#define INV_PTT 1140  // 12
#define INV_CST 1152  // 12
#define INV_CC  1164  // 144
#define ZERO_COUNT 168  // sst_s + stt + sstd must be zeroed (atomic targets)

__device__ __forceinline__ float kern5(float d, const float* __restrict__ ibw) {
    float acc = 0.f;
#pragma unroll
    for (int k = 0; k < 5; k++) {
        float r = fminf(fmaxf(d * ibw[k], 1e-5f), 1e5f);
        acc += __expf(-r);
    }
    return acc;
}

__device__ __forceinline__ float blockReduceSum(float v, float* sh) {
#pragma unroll
    for (int o = 32; o; o >>= 1) v += __shfl_xor(v, o, 64);
    __syncthreads();                       // protect sh reuse across calls
    if ((threadIdx.x & 63) == 0) sh[threadIdx.x >> 6] = v;
    __syncthreads();
    float r = 0.f;
    if (threadIdx.x == 0) {
        int nw = (int)(blockDim.x >> 6);
        for (int w = 0; w < nw; w++) r += sh[w];
    }
    return r;
}

// ---------- kernel 1: three pairwise-distance matrices (+ zero st/out) ----------
// z=0: E_ss = dist(src,src); z=1: E_tt = dist(tgt,tgt); z=2: E_st = dist(src,tgt)
__global__ __launch_bounds__(256) void cdist_kernel(
        const float* __restrict__ sx, const float* __restrict__ tx,
        float* __restrict__ Ebase, float* __restrict__ st, float* __restrict__ out) {
    int z = blockIdx.z;
    int tid = threadIdx.x;
    // fold the memsets into one block; stats/eval only run after this kernel
    // fully completes (stream order), so this is race-free.
    if (z == 0 && blockIdx.x == 0 && blockIdx.y == 0) {
        if (tid < ZERO_COUNT) st[tid] = 0.f;
        if (tid < 2) out[tid] = 0.f;
    }
    const float* X = (z == 1) ? tx : sx;
    const float* Y = (z == 0) ? sx : tx;
    float* Eo = Ebase + z * NN;
    __shared__ float As[32][33];
    __shared__ float Bs[32][33];
    int i0 = blockIdx.y * 32, j0 = blockIdx.x * 32;
    int tj = tid & 31, ti = tid >> 5;  // 32 cols x 8 rows
    float acc[4] = {0.f, 0.f, 0.f, 0.f};
    for (int kk = 0; kk < Dd; kk += 32) {
#pragma unroll
        for (int p = 0; p < 4; p++) {
            int idx = tid + p * 256;
            int r = idx >> 5, k = idx & 31;
            As[r][k] = X[(i0 + r) * Dd + kk + k];
            Bs[r][k] = Y[(j0 + r) * Dd + kk + k];
        }
        __syncthreads();
#pragma unroll
        for (int m = 0; m < 4; m++) {
            int r = ti + m * 8;
            float a = 0.f;
#pragma unroll
            for (int k = 0; k < 32; k++) {
                float d = As[r][k] - Bs[tj][k];
                a = fmaf(d, d, a);
            }
            acc[m] += a;
        }
        __syncthreads();
    }
#pragma unroll
    for (int m = 0; m < 4; m++)
        Eo[(i0 + ti + m * 8) * Nn + j0 + tj] = sqrtf(acc[m]);
}

// ---------- kernel 2: class-weighted distance sums ----------
// grid (48 row-chunks of 8, 3 matrices), block 384 (thread = column j)
__global__ __launch_bounds__(384) void stats_kernel(
        const float* __restrict__ Ebase, const int* __restrict__ ys,
        const float* __restrict__ pt, float* __restrict__ st) {
    int z = blockIdx.y;
    int i0 = blockIdx.x * 8;
    int j = threadIdx.x;
    const float* E = Ebase + z * NN;
    __shared__ int ysh[8];
    __shared__ float ptish[96];
    __shared__ float red[144];
    if (j < 8) ysh[j] = ys[i0 + j];
    if (j < 144) red[j] = 0.f;
    if (j < 96) ptish[j] = pt[i0 * 12 + j];  // rows i0..i0+7 of pt
    __syncthreads();

    float acc[12];
#pragma unroll
    for (int c = 0; c < 12; c++) acc[c] = 0.f;

    if (z == 0) {
        // sst_s[s][t] = sum_{i in s, j in t} E_ss[i,j]
        for (int r = 0; r < 8; r++) {
            int s = ysh[r];
            float e = E[(i0 + r) * Nn + j];
#pragma unroll
            for (int c = 0; c < 12; c++) acc[c] += (s == c) ? e : 0.f;
        }
        int t = ys[j];
#pragma unroll
        for (int c = 0; c < 12; c++)
            if (acc[c] != 0.f) atomicAdd(&red[c * 12 + t], acc[c]);
        __syncthreads();
        if (j < 144 && red[j] != 0.f) atomicAdd(&st[SST_S + j], red[j]);
    } else if (z == 1) {
        // stt[c] = sum_ij pt[i,c] E_tt[i,j] pt[j,c]
        for (int r = 0; r < 8; r++) {
            float e = E[(i0 + r) * Nn + j];
#pragma unroll
            for (int c = 0; c < 12; c++) acc[c] = fmaf(e, ptish[r * 12 + c], acc[c]);
        }
#pragma unroll
        for (int c = 0; c < 12; c++) {
            float v = acc[c] * pt[j * 12 + c];
#pragma unroll
            for (int o = 32; o; o >>= 1) v += __shfl_xor(v, o, 64);
            if ((j & 63) == 0) atomicAdd(&red[c], v);
        }
        __syncthreads();
        if (j < 12) atomicAdd(&st[STT + j], red[j]);
    } else {
        // sstd[c] = sum_{i in c, j} E_st[i,j] pt[j,c]
        for (int r = 0; r < 8; r++) {
            int s = ysh[r];
            float e = E[(i0 + r) * Nn + j];
#pragma unroll
            for (int c = 0; c < 12; c++) acc[c] += (s == c) ? e : 0.f;
        }
#pragma unroll
        for (int c = 0; c < 12; c++) {
            float v = acc[c] * pt[j * 12 + c];
#pragma unroll
            for (int o = 32; o; o >>= 1) v += __shfl_xor(v, o, 64);
            if ((j & 63) == 0) atomicAdd(&red[c], v);
        }
        __syncthreads();
        if (j < 12) atomicAdd(&st[SSTD + j], red[j]);
    }
}

// ---------- kernel 3: counts, gammas, inverse-bandwidth tables ----------
__global__ __launch_bounds__(256) void prep_kernel(
        const int* __restrict__ ys, const float* __restrict__ pt,
        float* __restrict__ st) {
    const float MUP[5] = {0.25f, 0.5f, 1.f, 2.f, 4.f};
    __shared__ float csh[12], cth[12];
    int tid = threadIdx.x;
    if (tid < 12) { csh[tid] = 0.f; cth[tid] = 0.f; }
    __syncthreads();
    float myc[12], myt[12];
#pragma unroll
    for (int c = 0; c < 12; c++) { myc[c] = 0.f; myt[c] = 0.f; }
    for (int i = tid; i < Nn; i += 256) {
        int y = ys[i];
#pragma unroll
        for (int c = 0; c < 12; c++) {
            myc[c] += (y == c) ? 1.f : 0.f;
            myt[c] += pt[i * 12 + c];
        }
    }
#pragma unroll
    for (int c = 0; c < 12; c++) {
        float a = myc[c], b = myt[c];
#pragma unroll
        for (int o = 32; o; o >>= 1) { a += __shfl_xor(a, o, 64); b += __shfl_xor(b, o, 64); }
        if ((tid & 63) == 0) { atomicAdd(&csh[c], a); atomicAdd(&cth[c], b); }
    }
    __syncthreads();

    if (tid < 12) {
        float cs = csh[tid], ct = cth[tid];
        st[CS + tid] = cs;
        st[CT + tid] = ct;
        float sss = st[SST_S + tid * 13];
        float den = (cs + ct) * (cs + ct);
        float g = (sss + st[STT + tid] + 2.f * st[SSTD + tid]) / den;
        st[G_IN + tid] = g;
#pragma unroll
        for (int k = 0; k < 5; k++)
            st[IBW_IN + tid * 5 + k] = 1.f / fmaxf(g * MUP[k], 1e-5f);
        st[INV_PSS + tid] = 1.f / (cs * cs);
        st[INV_PTT + tid] = 1.f / (ct * ct);
        st[INV_CST + tid] = 1.f / (cs * ct);
    }
    if (tid < 144) {
        int s = tid / 12, t = tid % 12;
        float cs = csh[s], ctc = csh[t];
        float sums = st[SST_S + s * 13], sumt = st[SST_S + t * 13];
        float den = (cs + ctc) * (cs + ctc);
        float g2 = (sums + sumt + 2.f * st[SST_S + tid]) / den;
        st[G2 + tid] = g2;
#pragma unroll
        for (int k = 0; k < 5; k++)
            st[IBW2 + tid * 5 + k] = 1.f / fmaxf(g2 * MUP[k], 1e-5f);
        st[INV_CC + tid] = 1.f / (cs * ctc);
    }
}

// ---------- kernel 4: fused evaluation (k1 + k2 + k3 + inter T1/T2/T3) ----------
// One block per row i (384 blocks x 384 threads): thread j handles pair (i,j)
// of all three E matrices. s = ys[i] is BLOCK-UNIFORM -> only row s of the
// ibw2 table is needed (60 floats, broadcast LDS reads).
__global__ __launch_bounds__(384) void eval_kernel(
        const float* __restrict__ E, const int* __restrict__ ys,
        const float* __restrict__ pt, const float* __restrict__ st,
        float* __restrict__ out) {
    int i = blockIdx.x;
    int j = threadIdx.x;
    int s = ys[i];                         // uniform broadcast load
    __shared__ float sh_ibwin[60];         // 1/bw(g_in), all classes (k2, k3, k1)
    __shared__ float sh_ibw2s[60];         // 1/bw(g2), row s (inter terms)
    __shared__ float sh_invptt[12];
    __shared__ float sh_invccs[12];        // 1/(cs[s]*cs[t]), row s
    __shared__ float sh_pti[12];           // pt[i][*]
    __shared__ float red[8];
    if (j < 60)                      sh_ibwin[j]        = st[IBW_IN + j];
    else if (j >= 64 && j < 124)     sh_ibw2s[j - 64]   = st[IBW2 + s * 60 + (j - 64)];
    else if (j >= 128 && j < 140)    sh_invptt[j - 128] = st[INV_PTT + (j - 128)];
    else if (j >= 192 && j < 204)    sh_invccs[j - 192] = st[INV_CC + s * 12 + (j - 192)];
    else if (j >= 256 && j < 268)    sh_pti[j - 256]    = pt[i * 12 + (j - 256)];
    float invpss_s = st[INV_PSS + s];
    float invcst_s = st[INV_CST + s];
    float e_ss = E[i * Nn + j];
    float e_tt = E[NN + i * Nn + j];
    float e_st = E[2 * NN + i * Nn + j];
    int t = ys[j];
    // pt row j: 48B aligned -> 3x float4
    const float4* p4 = (const float4*)(pt + j * 12);
    float4 pa = p4[0], pb = p4[1], pc = p4[2];
    float ptj[12] = {pa.x, pa.y, pa.z, pa.w, pb.x, pb.y, pb.z, pb.w,
                     pc.x, pc.y, pc.z, pc.w};
    __syncthreads();

    float si = 0.f, se = 0.f;
    // ---- k2: target-target, soft probs, all 12 classes (60 exps) ----
#pragma unroll
    for (int c = 0; c < 12; c++) {
        float w = sh_pti[c] * ptj[c];
        si = fmaf(kern5(e_tt * w, &sh_ibwin[c * 5]) * w, sh_invptt[c], si);
    }
    // ---- k3: source-target, diagonal pair (class s) (5 exps) ----
    {
        float w = 0.f;                     // ptj[s] via unrolled select (no scratch)
#pragma unroll
        for (int c = 0; c < 12; c++) w = (c == s) ? ptj[c] : w;
        si = fmaf(-2.f * kern5(e_st * w, &sh_ibwin[s * 5]) * w, invcst_s, si);
    }
    // ---- k1 + inter on E_ss ----
    if (t == s) {
        si = fmaf(kern5(e_ss, &sh_ibwin[s * 5]), invpss_s, si);
        float ts = -kern5(e_ss, &sh_ibw2s[s * 5]);  // subtract tp==s term
#pragma unroll
        for (int tp = 0; tp < 12; tp++)
            ts += kern5(e_ss, &sh_ibw2s[tp * 5]);
        se = fmaf(2.f * ts, invpss_s, se);
    } else {
        se = fmaf(-2.f * kern5(e_ss, &sh_ibw2s[t * 5]), sh_invccs[t], se);
    }
    si = blockReduceSum(si, red);
    se = blockReduceSum(se, red);
    if (j == 0) {
        atomicAdd(&out[0], si * (1.f / 12.f));
        atomicAdd(&out[1], se * (1.f / 132.f));   // C*C - C = 132
    }
}

extern "C" void kernel_launch(void* const* d_in, const int* in_sizes, int n_in,
                              void* d_out, int out_size, void* d_ws, size_t ws_size,
                              hipStream_t stream) {
    (void)in_sizes; (void)n_in; (void)out_size; (void)ws_size;
    const float* sx = (const float*)d_in[0];   // src_x (384,256) f32
    const float* tx = (const float*)d_in[1];   // tgt_x (384,256) f32
    const int*   ys = (const int*)d_in[2];     // src_y (384,) i32
    const float* pt = (const float*)d_in[3];   // tgt_y (384,12) f32
    float* out = (float*)d_out;                // [intra, inter] f32
    float* ws  = (float*)d_ws;
    float* E   = ws;                           // 3 * NN floats
    float* st  = ws + 3 * NN;                  // stats block

    cdist_kernel<<<dim3(12, 12, 3), 256, 0, stream>>>(sx, tx, E, st, out);
    stats_kernel<<<dim3(48, 3), 384, 0, stream>>>(E, ys, pt, st);
    prep_kernel<<<1, 256, 0, stream>>>(ys, pt, st);
    eval_kernel<<<384, 384, 0, stream>>>(E, ys, pt, st, out);
}